// Round 5
// baseline (467.218 us; speedup 1.0000x reference)
//
#include <hip/hip_runtime.h>
#include <hip/hip_bf16.h>
#include <stdint.h>

typedef unsigned short u16;
typedef __attribute__((ext_vector_type(4))) float f32x4;
typedef __attribute__((ext_vector_type(8))) short bf16x8;
typedef __attribute__((ext_vector_type(4))) unsigned short u16x4;
typedef __attribute__((ext_vector_type(8))) unsigned short u16x8;

__device__ inline u16 f2bf(float f) {
    unsigned int u = __builtin_bit_cast(unsigned int, f);
    u = u + 0x7fffu + ((u >> 16) & 1u);
    return (u16)(u >> 16);
}
__device__ inline float bf2f(u16 h) {
    return __builtin_bit_cast(float, ((unsigned int)h) << 16);
}
__device__ inline void gld_lds16(const void* g, void* l) {
    __builtin_amdgcn_global_load_lds((__attribute__((address_space(1))) void*)(g),
                                     (__attribute__((address_space(3))) void*)(l),
                                     16, 0, 0);
}

#define SB0() __builtin_amdgcn_sched_barrier(0)
#define BARRIER() do { __builtin_amdgcn_s_barrier(); SB0(); } while (0)

// ---------------------------------------------------------------------------
// 256x256 NT GEMM, BK=64, 512 thr = 8 waves (2M x 4N), 128x64 out per wave.
// 4 phases per K-tile, ONE barrier per phase. All 24 ds_reads of the tile are
// front-loaded into phase 0; the compiler inserts counted lgkm waits before
// each MFMA cluster (a0+b0 -> a1 -> b1), overlapping ds_read latency with
// MFMA. Stages: ph0 B0(t+1), ph1 B1(t+1), ph2 A0(t+2), ph3 A1(t+2); counted
// vmcnt(4) once per tile (never 0 in steady state). t-loop unrolled by 2 so
// LDS buffer addresses are compile-time static.
//
// Hazard audit: B(t+1) writes buf[t+1] B whose reads (tile t-1) retired >=2
// barriers earlier. A(t+2) writes buf[cur] A; a0/a1 reads execute before ph1
// MFMA (compiler wait) -> before ph1-end barrier -> stage issued after.
// vmcnt induction: start of tile t has A(t+1) x2halves in flight (4 loads);
// +8 staged during tile -> 12; vmcnt(4) retires A(t+1),B(t+1) leaving A(t+2).
// Tail t>=NT-2 stages no-op -> vmcnt(0).
// ---------------------------------------------------------------------------
template <int BF16OUT, int BIAS>
__global__ __launch_bounds__(512, 2)
void gemm256(const u16* __restrict__ A, const u16* __restrict__ B,
             void* __restrict__ Cv, const float* __restrict__ bias,
             int K, int lda, int ldb, int ldc,
             long sAb, long sBb, long sCb, float scale)
{
    __shared__ __align__(16) char lds[131072];

    const int tid  = threadIdx.x;
    const int lane = tid & 63;
    const int w    = tid >> 6;
    const int wm   = w >> 2, wn = w & 3;

    // XCD-aware bijective block swizzle (nwg % 8 == 0 for all our grids)
    const int gx   = gridDim.x, gy = gridDim.y;
    const int flat = blockIdx.x + gx * (blockIdx.y + gy * blockIdx.z);
    const int nwg  = gx * gy * gridDim.z;
    const int swz  = (flat & 7) * (nwg >> 3) + (flat >> 3);
    const int mt   = swz % gx;
    const int rest = swz / gx;
    const int ntl  = rest % gy;
    const int zb   = rest / gy;

    const u16* Ab = A + (long)zb * sAb;
    const u16* Bb = B + (long)zb * sBb;
    const long rowA0 = (long)mt * 256;
    const long rowB0 = (long)ntl * 256;

    // staging geometry: wave w covers rows w*16 + {0,8} + (lane>>3) of a half
    const int srow   = w * 16 + (lane >> 3);
    const int schunk = (lane & 7) ^ ((lane >> 3) & 7);
    const u16* aG = Ab + (rowA0 + srow) * (long)lda + schunk * 8;
    const u16* bG = Bb + (rowB0 + srow) * (long)ldb + schunk * 8;

    const int NT = K >> 6;

    auto stageA = [&](int t, int hh) {
        if (t >= NT) return;
        const u16* s = aG + (long)hh * 128 * lda + (long)t * 64;
        char* d = lds + (t & 1) * 65536 + hh * 16384 + w * 2048;
        gld_lds16(s, d);
        gld_lds16(s + 8 * (long)lda, d + 1024);
    };
    auto stageB = [&](int t, int hh) {
        if (t >= NT) return;
        const u16* s = bG + (long)hh * 128 * ldb + (long)t * 64;
        char* d = lds + (t & 1) * 65536 + 32768 + hh * 16384 + w * 2048;
        gld_lds16(s, d);
        gld_lds16(s + 8 * (long)ldb, d + 1024);
    };

    const int rl    = lane & 15;
    const int kbyte = (lane >> 4) * 16;
    auto ldA = [&](int cur, int m, int kh) -> bf16x8 {
        const int row = wm * 128 + m * 16 + rl;
        const int byt = (kh * 64 + kbyte) ^ ((row & 7) << 4);
        return *(const bf16x8*)(lds + cur * 65536 + row * 128 + byt);
    };
    auto ldB = [&](int cur, int n, int kh) -> bf16x8 {
        const int row = wn * 64 + n * 16 + rl;
        const int byt = (kh * 64 + kbyte) ^ ((row & 7) << 4);
        return *(const bf16x8*)(lds + cur * 65536 + 32768 + row * 128 + byt);
    };

    f32x4 acc[8][4] = {};
    bf16x8 a0[4][2], a1[4][2], b0[2][2], b1[2][2];

    // prologue: tile0 fully + tile1 A-halves; leave A(1) pair in flight
    stageA(0, 0); stageA(0, 1);
    stageB(0, 0); stageB(0, 1);
    stageA(1, 0); stageA(1, 1);
    asm volatile("s_waitcnt vmcnt(4)" ::: "memory");
    BARRIER();

    auto tile = [&](int t, const int cur) {
        // ---- phase 0: stage B0(t+1); issue ALL 24 ds_reads; MFMA a0 x b0
        stageB(t + 1, 0);
#pragma unroll
        for (int m = 0; m < 4; ++m)
#pragma unroll
            for (int kh = 0; kh < 2; ++kh) a0[m][kh] = ldA(cur, m, kh);
#pragma unroll
        for (int n = 0; n < 2; ++n)
#pragma unroll
            for (int kh = 0; kh < 2; ++kh) b0[n][kh] = ldB(cur, n, kh);
#pragma unroll
        for (int m = 0; m < 4; ++m)
#pragma unroll
            for (int kh = 0; kh < 2; ++kh) a1[m][kh] = ldA(cur, m + 4, kh);
#pragma unroll
        for (int n = 0; n < 2; ++n)
#pragma unroll
            for (int kh = 0; kh < 2; ++kh) b1[n][kh] = ldB(cur, n + 2, kh);
        SB0();
        __builtin_amdgcn_s_setprio(1);
#pragma unroll
        for (int kh = 0; kh < 2; ++kh)
#pragma unroll
            for (int m = 0; m < 4; ++m)
#pragma unroll
                for (int n = 0; n < 2; ++n)
                    acc[m][n] = __builtin_amdgcn_mfma_f32_16x16x32_bf16(
                        a0[m][kh], b0[n][kh], acc[m][n], 0, 0, 0);
        __builtin_amdgcn_s_setprio(0);
        BARRIER();

        // ---- phase 1: stage B1(t+1); MFMA a1 x b0
        stageB(t + 1, 1);
        SB0();
        __builtin_amdgcn_s_setprio(1);
#pragma unroll
        for (int kh = 0; kh < 2; ++kh)
#pragma unroll
            for (int m = 0; m < 4; ++m)
#pragma unroll
                for (int n = 0; n < 2; ++n)
                    acc[m + 4][n] = __builtin_amdgcn_mfma_f32_16x16x32_bf16(
                        a1[m][kh], b0[n][kh], acc[m + 4][n], 0, 0, 0);
        __builtin_amdgcn_s_setprio(0);
        BARRIER();

        // ---- phase 2: stage A0(t+2); MFMA a1 x b1
        stageA(t + 2, 0);
        SB0();
        __builtin_amdgcn_s_setprio(1);
#pragma unroll
        for (int kh = 0; kh < 2; ++kh)
#pragma unroll
            for (int m = 0; m < 4; ++m)
#pragma unroll
                for (int n = 0; n < 2; ++n)
                    acc[m + 4][n + 2] = __builtin_amdgcn_mfma_f32_16x16x32_bf16(
                        a1[m][kh], b1[n][kh], acc[m + 4][n + 2], 0, 0, 0);
        __builtin_amdgcn_s_setprio(0);
        BARRIER();

        // ---- phase 3: stage A1(t+2); MFMA a0 x b1; boundary vmcnt
        stageA(t + 2, 1);
        SB0();
        __builtin_amdgcn_s_setprio(1);
#pragma unroll
        for (int kh = 0; kh < 2; ++kh)
#pragma unroll
            for (int m = 0; m < 4; ++m)
#pragma unroll
                for (int n = 0; n < 2; ++n)
                    acc[m][n + 2] = __builtin_amdgcn_mfma_f32_16x16x32_bf16(
                        a0[m][kh], b1[n][kh], acc[m][n + 2], 0, 0, 0);
        __builtin_amdgcn_s_setprio(0);
        if (t < NT - 2) { asm volatile("s_waitcnt vmcnt(4)" ::: "memory"); }
        else            { asm volatile("s_waitcnt vmcnt(0)" ::: "memory"); }
        BARRIER();
    };

    for (int t = 0; t < NT; t += 2) {  // NT is even (16 or 32)
        tile(t, 0);
        tile(t + 1, 1);
    }

    // epilogue: C/D layout col = lane&15, row = (lane>>4)*4 + j
#pragma unroll
    for (int m = 0; m < 8; ++m) {
#pragma unroll
        for (int n = 0; n < 4; ++n) {
            const long row0 = rowA0 + wm * 128 + m * 16 + (lane >> 4) * 4;
            const long col  = rowB0 + wn * 64 + n * 16 + (lane & 15);
            float bv = 0.0f;
            if (BIAS) bv = bias[col];
#pragma unroll
            for (int j = 0; j < 4; ++j) {
                const float val = acc[m][n][j] * scale + bv;
                const long  idx = (long)zb * sCb + (row0 + j) * ldc + col;
                if (BF16OUT) ((u16*)Cv)[idx] = f2bf(val);
                else         ((float*)Cv)[idx] = val;
            }
        }
    }
}

// ---------------------------------------------------------------------------
// In-place row softmax over 2048 bf16. One block (256 thr) per row.
// ---------------------------------------------------------------------------
__global__ __launch_bounds__(256)
void softmax_rows_bf16(u16* __restrict__ sc)
{
    __shared__ float redmax[4];
    __shared__ float redsum[4];
    const long row = blockIdx.x;
    u16x8* p = (u16x8*)(sc + row * 2048);
    const int t = threadIdx.x;

    u16x8 v = p[t];
    float f[8];
#pragma unroll
    for (int j = 0; j < 8; ++j) f[j] = bf2f(v[j]);

    float m = f[0];
#pragma unroll
    for (int j = 1; j < 8; ++j) m = fmaxf(m, f[j]);
#pragma unroll
    for (int o = 32; o; o >>= 1) m = fmaxf(m, __shfl_xor(m, o));
    if ((t & 63) == 0) redmax[t >> 6] = m;
    __syncthreads();
    m = fmaxf(fmaxf(redmax[0], redmax[1]), fmaxf(redmax[2], redmax[3]));

    float e[8], s = 0.0f;
#pragma unroll
    for (int j = 0; j < 8; ++j) { e[j] = __expf(f[j] - m); s += e[j]; }
#pragma unroll
    for (int o = 32; o; o >>= 1) s += __shfl_xor(s, o);
    if ((t & 63) == 0) redsum[t >> 6] = s;
    __syncthreads();
    s = redsum[0] + redsum[1] + redsum[2] + redsum[3];
    const float inv = 1.0f / s;

    u16x8 o;
#pragma unroll
    for (int j = 0; j < 8; ++j) o[j] = f2bf(e[j] * inv);
    p[t] = o;
}

// f32 -> bf16 elementwise, 4 elems/thread
__global__ __launch_bounds__(256)
void cvt_bf16(const float* __restrict__ src, u16* __restrict__ dst, long n4)
{
    const long i = (long)blockIdx.x * 256 + threadIdx.x;
    if (i >= n4) return;
    f32x4 v = ((const f32x4*)src)[i];
    u16x4 o;
#pragma unroll
    for (int j = 0; j < 4; ++j) o[j] = f2bf(v[j]);
    ((u16x4*)dst)[i] = o;
}

// x[b][n][d] f32 -> xb[b][n][d] bf16 (straight) + xT[b][d][n] bf16 (transposed)
__global__ __launch_bounds__(256)
void prep_x(const float* __restrict__ x, u16* __restrict__ xb, u16* __restrict__ xT)
{
    __shared__ float tile[32][33];
    const int  b  = blockIdx.z;
    const long n0 = (long)blockIdx.x * 32;
    const long d0 = (long)blockIdx.y * 32;
    const int  t  = threadIdx.x;
    const int  r  = t >> 3;
    const int  c  = (t & 7) * 4;

    f32x4 v = *(const f32x4*)(x + ((long)b * 2048 + n0 + r) * 1024 + d0 + c);
    u16x4 s;
#pragma unroll
    for (int j = 0; j < 4; ++j) { s[j] = f2bf(v[j]); tile[r][c + j] = v[j]; }
    *(u16x4*)(xb + ((long)b * 2048 + n0 + r) * 1024 + d0 + c) = s;
    __syncthreads();

    u16x4 o;
#pragma unroll
    for (int j = 0; j < 4; ++j) o[j] = f2bf(tile[c + j][r]);
    *(u16x4*)(xT + ((long)b * 1024 + d0 + r) * 2048 + n0 + c) = o;
}

// ---------------------------------------------------------------------------
// B=8, N=2048, DIM=1024.  ws layout (160 MB):
//   xT [8,1024,2048] bf16 @ 0      (32 MB)  live: prep -> PV
//   qk [16384,2048]  bf16 @ 32 MB  (64 MB)  live: proj -> scores
//   sc [8,2048,2048] bf16 @ 96 MB  (64 MB)  scores -> softmax -> PV
//   xb [8,2048,1024] bf16 @ 96 MB  (32 MB)  ALIAS under sc; dead before scores
//   Wb [2048,1024]   bf16 @ 128 MB ( 4 MB)  ALIAS under sc; dead before scores
// ---------------------------------------------------------------------------
extern "C" void kernel_launch(void* const* d_in, const int* in_sizes, int n_in,
                              void* d_out, int out_size, void* d_ws, size_t ws_size,
                              hipStream_t stream)
{
    const float* x   = (const float*)d_in[0];
    const float* Wqk = (const float*)d_in[1];
    const float* bqk = (const float*)d_in[2];
    float* out = (float*)d_out;

    char* ws = (char*)d_ws;
    u16* xT = (u16*)(ws);
    u16* qk = (u16*)(ws + 33554432L);
    u16* sc = (u16*)(ws + 100663296L);
    u16* xb = (u16*)(ws + 100663296L);
    u16* Wb = (u16*)(ws + 134217728L);

    cvt_bf16<<<2048, 256, 0, stream>>>(Wqk, Wb, 2048L * 1024 / 4);
    prep_x<<<dim3(64, 32, 8), 256, 0, stream>>>(x, xb, xT);

    // qk = x @ W^T + b  -> bf16 [16384, 2048]
    gemm256<1, 1><<<dim3(64, 8, 1), 512, 0, stream>>>(
        xb, Wb, qk, bqk, 1024, 1024, 1024, 2048, 0, 0, 0, 1.0f);

    // sc[b] = k_b @ q_b^T / 32 -> bf16 [2048, 2048] per batch
    gemm256<1, 0><<<dim3(8, 8, 8), 512, 0, stream>>>(
        qk + 1024, qk, sc, nullptr, 1024, 2048, 2048, 2048,
        2048L * 2048, 2048L * 2048, 2048L * 2048, 0.03125f);

    // sc = softmax(sc) in place
    softmax_rows_bf16<<<16384, 256, 0, stream>>>(sc);

    // out[b] = attn_b @ x_b  (NT with xT) -> f32 to d_out
    gemm256<0, 0><<<dim3(8, 4, 8), 512, 0, stream>>>(
        sc, xT, out, nullptr, 2048, 2048, 2048, 1024,
        2048L * 2048, 1024L * 2048, 2048L * 1024, 1.0f);
}

// Round 6
// 296.668 us; speedup vs baseline: 1.5749x; 1.5749x over previous
//
#include <hip/hip_runtime.h>
#include <hip/hip_bf16.h>
#include <stdint.h>

typedef unsigned short u16;
typedef __attribute__((ext_vector_type(4))) float f32x4;
typedef __attribute__((ext_vector_type(8))) short bf16x8;
typedef __attribute__((ext_vector_type(4))) unsigned short u16x4;
typedef __attribute__((ext_vector_type(8))) unsigned short u16x8;

__device__ inline u16 f2bf(float f) {
    unsigned int u = __builtin_bit_cast(unsigned int, f);
    u = u + 0x7fffu + ((u >> 16) & 1u);
    return (u16)(u >> 16);
}
__device__ inline float bf2f(u16 h) {
    return __builtin_bit_cast(float, ((unsigned int)h) << 16);
}
__device__ inline void gld_lds16(const void* g, void* l) {
    __builtin_amdgcn_global_load_lds((__attribute__((address_space(1))) void*)(g),
                                     (__attribute__((address_space(3))) void*)(l),
                                     16, 0, 0);
}

#define SB0() __builtin_amdgcn_sched_barrier(0)
#define BARRIER() do { __builtin_amdgcn_s_barrier(); SB0(); } while (0)

// ---------------------------------------------------------------------------
// 256x256 NT GEMM, BK=64, 512 thr = 8 waves (2M x 4N), 128x64 out per wave.
// 4 phases per K-tile, ONE barrier per phase (end). Reads distributed as in
// the proven round-3 schedule (ph0: a0+b0 = 12, ph1: a1 = 8, ph2: b1 = 4,
// ph3: none) so peak fragment liveness stays ~80 VGPR (no spill; round-5's
// front-loaded variant spilled ~118MB/dispatch). No explicit lgkm drain: the
// compiler inserts counted lgkmcnt before each MFMA cluster (m97 behavior),
// overlapping ds_read latency with stage-issue and MFMA.
//
// Hazards: stageB(t+1) writes buf[1-cur]: its b-reads retired in tile t-1
// before that tile's ph2-end barrier (>=2 barriers earlier). stageA(t+2)
// (ph2/ph3) writes buf[cur] A-region: every wave's a0/a1 reads retire before
// its own ph1 MFMAs (compiler lgkm dep), hence before the ph1-end barrier;
// stageA issues strictly after that barrier. buf[cur] fully landed before
// ph0 reads via end-of-(t-1) vmcnt(4)+barrier.
// vmcnt induction: at tile start 4 outstanding (= A(t+1)); +8 staged during
// tile = 12; vmcnt(4) retires A(t+1)+B(t+1), leaves A(t+2). Tail: vmcnt(0).
// ---------------------------------------------------------------------------
template <int BF16OUT, int BIAS>
__global__ __launch_bounds__(512, 2)
void gemm256(const u16* __restrict__ A, const u16* __restrict__ B,
             void* __restrict__ Cv, const float* __restrict__ bias,
             int K, int lda, int ldb, int ldc,
             long sAb, long sBb, long sCb, float scale)
{
    __shared__ __align__(16) char lds[131072];

    const int tid  = threadIdx.x;
    const int lane = tid & 63;
    const int w    = tid >> 6;
    const int wm   = w >> 2, wn = w & 3;

    // XCD-aware bijective block swizzle (nwg % 8 == 0 for all our grids)
    const int gx   = gridDim.x, gy = gridDim.y;
    const int flat = blockIdx.x + gx * (blockIdx.y + gy * blockIdx.z);
    const int nwg  = gx * gy * gridDim.z;
    const int swz  = (flat & 7) * (nwg >> 3) + (flat >> 3);
    const int mt   = swz % gx;
    const int rest = swz / gx;
    const int ntl  = rest % gy;
    const int zb   = rest / gy;

    const u16* Ab = A + (long)zb * sAb;
    const u16* Bb = B + (long)zb * sBb;
    const long rowA0 = (long)mt * 256;
    const long rowB0 = (long)ntl * 256;

    // staging geometry: wave w covers rows w*16 + {0,8} + (lane>>3) of a half
    const int srow   = w * 16 + (lane >> 3);
    const int schunk = (lane & 7) ^ ((lane >> 3) & 7);
    const u16* aG = Ab + (rowA0 + srow) * (long)lda + schunk * 8;
    const u16* bG = Bb + (rowB0 + srow) * (long)ldb + schunk * 8;

    const int NT = K >> 6;

    auto stageA = [&](int t, int hh) {
        if (t >= NT) return;
        const u16* s = aG + (long)hh * 128 * lda + (long)t * 64;
        char* d = lds + (t & 1) * 65536 + hh * 16384 + w * 2048;
        gld_lds16(s, d);
        gld_lds16(s + 8 * (long)lda, d + 1024);
    };
    auto stageB = [&](int t, int hh) {
        if (t >= NT) return;
        const u16* s = bG + (long)hh * 128 * ldb + (long)t * 64;
        char* d = lds + (t & 1) * 65536 + 32768 + hh * 16384 + w * 2048;
        gld_lds16(s, d);
        gld_lds16(s + 8 * (long)ldb, d + 1024);
    };

    const int rl    = lane & 15;
    const int kbyte = (lane >> 4) * 16;
    auto ldA = [&](int cur, int m, int kh) -> bf16x8 {
        const int row = wm * 128 + m * 16 + rl;
        const int byt = (kh * 64 + kbyte) ^ ((row & 7) << 4);
        return *(const bf16x8*)(lds + cur * 65536 + row * 128 + byt);
    };
    auto ldB = [&](int cur, int n, int kh) -> bf16x8 {
        const int row = wn * 64 + n * 16 + rl;
        const int byt = (kh * 64 + kbyte) ^ ((row & 7) << 4);
        return *(const bf16x8*)(lds + cur * 65536 + 32768 + row * 128 + byt);
    };

    f32x4 acc[8][4] = {};
    bf16x8 a0[4][2], a1[4][2], b0[2][2], b1[2][2];

    // prologue: tile0 fully + tile1 A-halves; leave A(1) pair in flight
    stageA(0, 0); stageA(0, 1);
    stageB(0, 0); stageB(0, 1);
    stageA(1, 0); stageA(1, 1);
    asm volatile("s_waitcnt vmcnt(4)" ::: "memory");
    BARRIER();

    auto tile = [&](int t, const int cur) {
        // ---- phase 0: stage B0(t+1); read a0,b0; MFMA a0 x b0
        stageB(t + 1, 0);
#pragma unroll
        for (int m = 0; m < 4; ++m)
#pragma unroll
            for (int kh = 0; kh < 2; ++kh) a0[m][kh] = ldA(cur, m, kh);
#pragma unroll
        for (int n = 0; n < 2; ++n)
#pragma unroll
            for (int kh = 0; kh < 2; ++kh) b0[n][kh] = ldB(cur, n, kh);
        __builtin_amdgcn_s_setprio(1);
#pragma unroll
        for (int kh = 0; kh < 2; ++kh)
#pragma unroll
            for (int m = 0; m < 4; ++m)
#pragma unroll
                for (int n = 0; n < 2; ++n)
                    acc[m][n] = __builtin_amdgcn_mfma_f32_16x16x32_bf16(
                        a0[m][kh], b0[n][kh], acc[m][n], 0, 0, 0);
        __builtin_amdgcn_s_setprio(0);
        BARRIER();

        // ---- phase 1: stage B1(t+1); read a1; MFMA a1 x b0
        stageB(t + 1, 1);
#pragma unroll
        for (int m = 0; m < 4; ++m)
#pragma unroll
            for (int kh = 0; kh < 2; ++kh) a1[m][kh] = ldA(cur, m + 4, kh);
        __builtin_amdgcn_s_setprio(1);
#pragma unroll
        for (int kh = 0; kh < 2; ++kh)
#pragma unroll
            for (int m = 0; m < 4; ++m)
#pragma unroll
                for (int n = 0; n < 2; ++n)
                    acc[m + 4][n] = __builtin_amdgcn_mfma_f32_16x16x32_bf16(
                        a1[m][kh], b0[n][kh], acc[m + 4][n], 0, 0, 0);
        __builtin_amdgcn_s_setprio(0);
        BARRIER();

        // ---- phase 2: stage A0(t+2); read b1; MFMA a1 x b1
        stageA(t + 2, 0);
#pragma unroll
        for (int n = 0; n < 2; ++n)
#pragma unroll
            for (int kh = 0; kh < 2; ++kh) b1[n][kh] = ldB(cur, n + 2, kh);
        __builtin_amdgcn_s_setprio(1);
#pragma unroll
        for (int kh = 0; kh < 2; ++kh)
#pragma unroll
            for (int m = 0; m < 4; ++m)
#pragma unroll
                for (int n = 0; n < 2; ++n)
                    acc[m + 4][n + 2] = __builtin_amdgcn_mfma_f32_16x16x32_bf16(
                        a1[m][kh], b1[n][kh], acc[m + 4][n + 2], 0, 0, 0);
        __builtin_amdgcn_s_setprio(0);
        BARRIER();

        // ---- phase 3: stage A1(t+2); MFMA a0 x b1; boundary vmcnt
        stageA(t + 2, 1);
        __builtin_amdgcn_s_setprio(1);
#pragma unroll
        for (int kh = 0; kh < 2; ++kh)
#pragma unroll
            for (int m = 0; m < 4; ++m)
#pragma unroll
                for (int n = 0; n < 2; ++n)
                    acc[m][n + 2] = __builtin_amdgcn_mfma_f32_16x16x32_bf16(
                        a0[m][kh], b1[n][kh], acc[m][n + 2], 0, 0, 0);
        __builtin_amdgcn_s_setprio(0);
        if (t < NT - 2) { asm volatile("s_waitcnt vmcnt(4)" ::: "memory"); }
        else            { asm volatile("s_waitcnt vmcnt(0)" ::: "memory"); }
        SB0();
        BARRIER();
    };

    for (int t = 0; t < NT; t += 2) {  // NT is even (16 or 32)
        tile(t, 0);
        tile(t + 1, 1);
    }

    // epilogue: C/D layout col = lane&15, row = (lane>>4)*4 + j
#pragma unroll
    for (int m = 0; m < 8; ++m) {
#pragma unroll
        for (int n = 0; n < 4; ++n) {
            const long row0 = rowA0 + wm * 128 + m * 16 + (lane >> 4) * 4;
            const long col  = rowB0 + wn * 64 + n * 16 + (lane & 15);
            float bv = 0.0f;
            if (BIAS) bv = bias[col];
#pragma unroll
            for (int j = 0; j < 4; ++j) {
                const float val = acc[m][n][j] * scale + bv;
                const long  idx = (long)zb * sCb + (row0 + j) * ldc + col;
                if (BF16OUT) ((u16*)Cv)[idx] = f2bf(val);
                else         ((float*)Cv)[idx] = val;
            }
        }
    }
}

// ---------------------------------------------------------------------------
// In-place row softmax over 2048 bf16. One block (256 thr) per row.
// ---------------------------------------------------------------------------
__global__ __launch_bounds__(256)
void softmax_rows_bf16(u16* __restrict__ sc)
{
    __shared__ float redmax[4];
    __shared__ float redsum[4];
    const long row = blockIdx.x;
    u16x8* p = (u16x8*)(sc + row * 2048);
    const int t = threadIdx.x;

    u16x8 v = p[t];
    float f[8];
#pragma unroll
    for (int j = 0; j < 8; ++j) f[j] = bf2f(v[j]);

    float m = f[0];
#pragma unroll
    for (int j = 1; j < 8; ++j) m = fmaxf(m, f[j]);
#pragma unroll
    for (int o = 32; o; o >>= 1) m = fmaxf(m, __shfl_xor(m, o));
    if ((t & 63) == 0) redmax[t >> 6] = m;
    __syncthreads();
    m = fmaxf(fmaxf(redmax[0], redmax[1]), fmaxf(redmax[2], redmax[3]));

    float e[8], s = 0.0f;
#pragma unroll
    for (int j = 0; j < 8; ++j) { e[j] = __expf(f[j] - m); s += e[j]; }
#pragma unroll
    for (int o = 32; o; o >>= 1) s += __shfl_xor(s, o);
    if ((t & 63) == 0) redsum[t >> 6] = s;
    __syncthreads();
    s = redsum[0] + redsum[1] + redsum[2] + redsum[3];
    const float inv = 1.0f / s;

    u16x8 o;
#pragma unroll
    for (int j = 0; j < 8; ++j) o[j] = f2bf(e[j] * inv);
    p[t] = o;
}

// f32 -> bf16 elementwise, 4 elems/thread
__global__ __launch_bounds__(256)
void cvt_bf16(const float* __restrict__ src, u16* __restrict__ dst, long n4)
{
    const long i = (long)blockIdx.x * 256 + threadIdx.x;
    if (i >= n4) return;
    f32x4 v = ((const f32x4*)src)[i];
    u16x4 o;
#pragma unroll
    for (int j = 0; j < 4; ++j) o[j] = f2bf(v[j]);
    ((u16x4*)dst)[i] = o;
}

// x[b][n][d] f32 -> xb[b][n][d] bf16 (straight) + xT[b][d][n] bf16 (transposed)
__global__ __launch_bounds__(256)
void prep_x(const float* __restrict__ x, u16* __restrict__ xb, u16* __restrict__ xT)
{
    __shared__ float tile[32][33];
    const int  b  = blockIdx.z;
    const long n0 = (long)blockIdx.x * 32;
    const long d0 = (long)blockIdx.y * 32;
    const int  t  = threadIdx.x;
    const int  r  = t >> 3;
    const int  c  = (t & 7) * 4;

    f32x4 v = *(const f32x4*)(x + ((long)b * 2048 + n0 + r) * 1024 + d0 + c);
    u16x4 s;
#pragma unroll
    for (int j = 0; j < 4; ++j) { s[j] = f2bf(v[j]); tile[r][c + j] = v[j]; }
    *(u16x4*)(xb + ((long)b * 2048 + n0 + r) * 1024 + d0 + c) = s;
    __syncthreads();

    u16x4 o;
#pragma unroll
    for (int j = 0; j < 4; ++j) o[j] = f2bf(tile[c + j][r]);
    *(u16x4*)(xT + ((long)b * 1024 + d0 + r) * 2048 + n0 + c) = o;
}

// ---------------------------------------------------------------------------
// B=8, N=2048, DIM=1024.  ws layout (160 MB):
//   xT [8,1024,2048] bf16 @ 0      (32 MB)  live: prep -> PV
//   qk [16384,2048]  bf16 @ 32 MB  (64 MB)  live: proj -> scores
//   sc [8,2048,2048] bf16 @ 96 MB  (64 MB)  scores -> softmax -> PV
//   xb [8,2048,1024] bf16 @ 96 MB  (32 MB)  ALIAS under sc; dead before scores
//   Wb [2048,1024]   bf16 @ 128 MB ( 4 MB)  ALIAS under sc; dead before scores
// ---------------------------------------------------------------------------
extern "C" void kernel_launch(void* const* d_in, const int* in_sizes, int n_in,
                              void* d_out, int out_size, void* d_ws, size_t ws_size,
                              hipStream_t stream)
{
    const float* x   = (const float*)d_in[0];
    const float* Wqk = (const float*)d_in[1];
    const float* bqk = (const float*)d_in[2];
    float* out = (float*)d_out;

    char* ws = (char*)d_ws;
    u16* xT = (u16*)(ws);
    u16* qk = (u16*)(ws + 33554432L);
    u16* sc = (u16*)(ws + 100663296L);
    u16* xb = (u16*)(ws + 100663296L);
    u16* Wb = (u16*)(ws + 134217728L);

    cvt_bf16<<<2048, 256, 0, stream>>>(Wqk, Wb, 2048L * 1024 / 4);
    prep_x<<<dim3(64, 32, 8), 256, 0, stream>>>(x, xb, xT);

    // qk = x @ W^T + b  -> bf16 [16384, 2048]
    gemm256<1, 1><<<dim3(64, 8, 1), 512, 0, stream>>>(
        xb, Wb, qk, bqk, 1024, 1024, 1024, 2048, 0, 0, 0, 1.0f);

    // sc[b] = k_b @ q_b^T / 32 -> bf16 [2048, 2048] per batch
    gemm256<1, 0><<<dim3(8, 8, 8), 512, 0, stream>>>(
        qk + 1024, qk, sc, nullptr, 1024, 2048, 2048, 2048,
        2048L * 2048, 2048L * 2048, 2048L * 2048, 0.03125f);

    // sc = softmax(sc) in place
    softmax_rows_bf16<<<16384, 256, 0, stream>>>(sc);

    // out[b] = attn_b @ x_b  (NT with xT) -> f32 to d_out
    gemm256<0, 0><<<dim3(8, 4, 8), 512, 0, stream>>>(
        sc, xT, out, nullptr, 2048, 2048, 2048, 1024,
        2048L * 2048, 1024L * 2048, 2048L * 1024, 1.0f);
}